// Round 1
// baseline (932.993 us; speedup 1.0000x reference)
//
#include <hip/hip_runtime.h>
#include <hip/hip_bf16.h>

#define DEVI __device__ __forceinline__

typedef float f32x4 __attribute__((ext_vector_type(4)));
typedef short bf16x8 __attribute__((ext_vector_type(8)));
typedef unsigned short u16x4 __attribute__((ext_vector_type(4)));

// B=16, H=16, N=1024, E=1024, D=64; M = B*N = 16384

DEVI unsigned short f2bf(float f) {
  union { float f; unsigned u; } v; v.f = f;
  unsigned r = v.u + 0x7fffu + ((v.u >> 16) & 1u);  // RNE
  return (unsigned short)(r >> 16);
}

DEVI void gload_lds16(const unsigned short* g, unsigned short* l) {
  __builtin_amdgcn_global_load_lds(
      (const __attribute__((address_space(1))) void*)g,
      (__attribute__((address_space(3))) void*)l, 16, 0, 0);
}

// ---------------- fp32 -> bf16 conversion ----------------
__global__ void cvt_kernel(const float* __restrict__ s, unsigned short* __restrict__ d, int n4) {
  int i = blockIdx.x * blockDim.x + threadIdx.x;
  const int st = gridDim.x * blockDim.x;
  for (; i < n4; i += st) {
    const float4 v = reinterpret_cast<const float4*>(s)[i];
    u16x4 o;
    o[0] = f2bf(v.x); o[1] = f2bf(v.y); o[2] = f2bf(v.z); o[3] = f2bf(v.w);
    reinterpret_cast<u16x4*>(d)[i] = o;
  }
}

// ---------------- shared 128x128x(K=1024) bf16 GEMM mainloop (B^T form) ----------------
DEVI void gemm_tile(const unsigned short* __restrict__ A,
                    const unsigned short* __restrict__ Bw,
                    int m0, int n0,
                    unsigned short* lsA, unsigned short* lsB,
                    f32x4 acc[4][4]) {
  const int tid = threadIdx.x;
  const int w = tid >> 6, l = tid & 63, lg = l >> 4, lr = l & 15;
  const int wr = w >> 1, wc = w & 1;
  for (int kt = 0; kt < 1024; kt += 64) {
#pragma unroll
    for (int i = 0; i < 4; i++) {
      const int c = i * 256 + tid;
      const int row = c >> 3, col = (c & 7) * 8;
      gload_lds16(&A[(m0 + row) * 1024 + kt + col], &lsA[(i * 256 + w * 64) * 8]);
      gload_lds16(&Bw[(n0 + row) * 1024 + kt + col], &lsB[(i * 256 + w * 64) * 8]);
    }
    __syncthreads();
#pragma unroll
    for (int ks = 0; ks < 2; ks++) {
      bf16x8 af[4], bf_[4];
#pragma unroll
      for (int fi = 0; fi < 4; fi++) af[fi] = *(const bf16x8*)&lsA[(wr * 64 + fi * 16 + lr) * 64 + ks * 32 + lg * 8];
#pragma unroll
      for (int fj = 0; fj < 4; fj++) bf_[fj] = *(const bf16x8*)&lsB[(wc * 64 + fj * 16 + lr) * 64 + ks * 32 + lg * 8];
#pragma unroll
      for (int fi = 0; fi < 4; fi++)
#pragma unroll
        for (int fj = 0; fj < 4; fj++)
          acc[fi][fj] = __builtin_amdgcn_mfma_f32_16x16x32_bf16(af[fi], bf_[fj], acc[fi][fj], 0, 0, 0);
    }
    __syncthreads();
  }
}

// ---------------- QKV projection with layout-specializing epilogues ----------------
// z=0: Q natural [b][n][e]; z=1: K swapped [b'][h'][n][d] = kproj[h'][b']; z=2: V^T [b][h][d][n]
__global__ __launch_bounds__(256, 2) void proj_qkv(
    const unsigned short* __restrict__ X, const unsigned short* __restrict__ W3,
    const float* __restrict__ bq, const float* __restrict__ bk, const float* __restrict__ bv,
    unsigned short* __restrict__ outq, unsigned short* __restrict__ outk, unsigned short* __restrict__ outv) {
  __shared__ unsigned short lsA[128 * 64];
  __shared__ unsigned short lsB[128 * 64];
  const int z = blockIdx.z;
  const int m0 = blockIdx.x * 128, n0 = blockIdx.y * 128;
  const unsigned short* Bw = W3 + z * 1048576;
  f32x4 acc[4][4];
  const f32x4 z4 = {0.f, 0.f, 0.f, 0.f};
#pragma unroll
  for (int i = 0; i < 4; i++)
#pragma unroll
    for (int j = 0; j < 4; j++) acc[i][j] = z4;
  gemm_tile(X, Bw, m0, n0, lsA, lsB, acc);

  const int tid = threadIdx.x;
  const int w = tid >> 6, l = tid & 63, lg = l >> 4, lr = l & 15, wr = w >> 1, wc = w & 1;
  const float* bias = (z == 0) ? bq : ((z == 1) ? bk : bv);
#pragma unroll
  for (int fi = 0; fi < 4; fi++) {
    const int mb = m0 + wr * 64 + fi * 16 + lg * 4;
#pragma unroll
    for (int fj = 0; fj < 4; fj++) {
      const int ncol = n0 + wc * 64 + fj * 16 + lr;
      const float bsv = bias[ncol];
      if (z == 0) {
#pragma unroll
        for (int r = 0; r < 4; r++) outq[(mb + r) * 1024 + ncol] = f2bf(acc[fi][fj][r] + bsv);
      } else if (z == 1) {
        const int hh = ncol >> 6, dd = ncol & 63;
#pragma unroll
        for (int r = 0; r < 4; r++) {
          const int m = mb + r;
          outk[((hh * 16 + (m >> 10)) * 1024 + (m & 1023)) * 64 + dd] = f2bf(acc[fi][fj][r] + bsv);
        }
      } else {
        const int hh = ncol >> 6, dd = ncol & 63;
        const int bb = mb >> 10, nn = mb & 1023;
        u16x4 pk;
#pragma unroll
        for (int r = 0; r < 4; r++) pk[r] = f2bf(acc[fi][fj][r] + bsv);
        *(u16x4*)&outv[((bb * 16 + hh) * 64 + dd) * 1024 + nn] = pk;
      }
    }
  }
}

// ---------------- output projection (fp32 out + bias) ----------------
__global__ __launch_bounds__(256, 2) void proj_out(
    const unsigned short* __restrict__ A, const unsigned short* __restrict__ Wp,
    const float* __restrict__ bias, float* __restrict__ out) {
  __shared__ unsigned short lsA[128 * 64];
  __shared__ unsigned short lsB[128 * 64];
  const int m0 = blockIdx.x * 128, n0 = blockIdx.y * 128;
  f32x4 acc[4][4];
  const f32x4 z4 = {0.f, 0.f, 0.f, 0.f};
#pragma unroll
  for (int i = 0; i < 4; i++)
#pragma unroll
    for (int j = 0; j < 4; j++) acc[i][j] = z4;
  gemm_tile(A, Wp, m0, n0, lsA, lsB, acc);
  const int tid = threadIdx.x;
  const int w = tid >> 6, l = tid & 63, lg = l >> 4, lr = l & 15, wr = w >> 1, wc = w & 1;
#pragma unroll
  for (int fi = 0; fi < 4; fi++) {
    const int mb = m0 + wr * 64 + fi * 16 + lg * 4;
#pragma unroll
    for (int fj = 0; fj < 4; fj++) {
      const int ncol = n0 + wc * 64 + fj * 16 + lr;
      const float bsv = bias[ncol];
#pragma unroll
      for (int r = 0; r < 4; r++) out[(mb + r) * 1024 + ncol] = acc[fi][fj][r] + bsv;
    }
  }
}

// ---------------- fused attention ----------------
// grid: b(16) x qtile(32 rows of 32). 8 waves. Phase A: wave=(qh, ksub) computes
// energy for ALL 16 h on its 16x16 (q,k) tile -> softmax over h is lane-local.
// att -> swizzled LDS. Phase B: wave=(qh, hgroup of 4) does PV from LDS att + global V^T.
__global__ __launch_bounds__(512, 2) void attn_k(
    const unsigned short* __restrict__ Q,   // [16][1024][1024]
    const unsigned short* __restrict__ K,   // [16][16][1024][64] (pre-swapped)
    const unsigned short* __restrict__ VT,  // [16][16][64][1024]
    unsigned short* __restrict__ O) {       // [16][1024][1024]
  __shared__ unsigned short att[16 * 32 * 64];  // 64 KB, [h][q][k], XOR-swizzled
  const int tid = threadIdx.x;
  const int w = tid >> 6, l = tid & 63, lg = l >> 4, lr = l & 15;
  const int b = blockIdx.x >> 5, qt = blockIdx.x & 31;
  const int qh = w >> 2, ksub = w & 3, hg = w & 3;

  f32x4 oacc[4][4];
  const f32x4 z4 = {0.f, 0.f, 0.f, 0.f};
#pragma unroll
  for (int i = 0; i < 4; i++)
#pragma unroll
    for (int j = 0; j < 4; j++) oacc[i][j] = z4;

  const unsigned short* Qrow = Q + (b * 1024 + qt * 32 + qh * 16 + lr) * 1024 + lg * 8;

  int awbase[4];
#pragma unroll
  for (int r = 0; r < 4; r++) {
    const int q = qh * 16 + lg * 4 + r;
    awbase[r] = (q * 64 + ksub * 16 + lr) ^ ((q & 7) << 3);
  }
  const int qB = qh * 16 + lr;
  const int swzB = (qB & 7) << 3;

  for (int kb0 = 0; kb0 < 1024; kb0 += 64) {
    const unsigned short* Qp = Qrow;
    asm volatile("" : "+v"(Qp));  // block LICM from hoisting 32 Q-frag loads (VGPR blowup)
    const unsigned short* Kp = K + ((b * 16) * 1024 + kb0 + ksub * 16 + lr) * 64 + lg * 8;

    // ---- phase A: energy for all 16 heads ----
    f32x4 e[16];
#pragma unroll
    for (int h = 0; h < 16; h++) {
      bf16x8 a0 = *(const bf16x8*)(Qp + h * 64);
      bf16x8 a1 = *(const bf16x8*)(Qp + h * 64 + 32);
      bf16x8 k0 = *(const bf16x8*)(Kp + h * 65536);
      bf16x8 k1 = *(const bf16x8*)(Kp + h * 65536 + 32);
      f32x4 t = __builtin_amdgcn_mfma_f32_16x16x32_bf16(a0, k0, z4, 0, 0, 0);
      e[h] = __builtin_amdgcn_mfma_f32_16x16x32_bf16(a1, k1, t, 0, 0, 0);
    }
    // ---- softmax over h (lane-local; |e|<~30 so exp is safe without max-sub) ----
#pragma unroll
    for (int r = 0; r < 4; r++) {
      float p[16];
      float s = 0.f;
#pragma unroll
      for (int h = 0; h < 16; h++) { p[h] = __expf(e[h][r]); s += p[h]; }
      const float inv = 1.0f / (s * 32.0f);  // scale=sqrt(E)=32 applied after softmax
#pragma unroll
      for (int h = 0; h < 16; h++) att[h * 2048 + awbase[r]] = f2bf(p[h] * inv);
    }
    __syncthreads();
    // ---- phase B: PV ----
#pragma unroll
    for (int hh = 0; hh < 4; hh++) {
      const int h = hg * 4 + hh;
      const unsigned short* Vp = VT + ((b * 16 + h) * 64 + lr) * 1024 + kb0 + lg * 8;
#pragma unroll
      for (int kst = 0; kst < 2; kst++) {
        bf16x8 pa = *(const bf16x8*)&att[h * 2048 + ((qB * 64 + kst * 32 + lg * 8) ^ swzB)];
#pragma unroll
        for (int dt = 0; dt < 4; dt++) {
          bf16x8 vb = *(const bf16x8*)(Vp + dt * 16384 + kst * 32);
          oacc[hh][dt] = __builtin_amdgcn_mfma_f32_16x16x32_bf16(pa, vb, oacc[hh][dt], 0, 0, 0);
        }
      }
    }
    __syncthreads();
  }

#pragma unroll
  for (int hh = 0; hh < 4; hh++) {
    const int h = hg * 4 + hh;
#pragma unroll
    for (int dt = 0; dt < 4; dt++) {
#pragma unroll
      for (int r = 0; r < 4; r++) {
        const int n = qt * 32 + qh * 16 + lg * 4 + r;
        O[(b * 1024 + n) * 1024 + h * 64 + dt * 16 + lr] = f2bf(oacc[hh][dt][r]);
      }
    }
  }
}

extern "C" void kernel_launch(void* const* d_in, const int* in_sizes, int n_in,
                              void* d_out, int out_size, void* d_ws, size_t ws_size,
                              hipStream_t stream) {
  const float* x  = (const float*)d_in[0];
  const float* Wq = (const float*)d_in[1];
  const float* bq = (const float*)d_in[2];
  const float* Wk = (const float*)d_in[3];
  const float* bk = (const float*)d_in[4];
  const float* Wv = (const float*)d_in[5];
  const float* bv = (const float*)d_in[6];
  const float* Wp = (const float*)d_in[7];
  const float* bp = (const float*)d_in[8];

  char* ws = (char*)d_ws;
  unsigned short* xbf  = (unsigned short*)(ws);              // 32 MiB; reused for o after attention
  unsigned short* qbf  = (unsigned short*)(ws + 33554432);
  unsigned short* kbf  = (unsigned short*)(ws + 67108864);
  unsigned short* vtbf = (unsigned short*)(ws + 100663296);
  unsigned short* wbf  = (unsigned short*)(ws + 134217728);  // Wq,Wk,Wv,Wp bf16 (4 x 2 MiB)

  cvt_kernel<<<2048, 256, 0, stream>>>(x, xbf, 4194304);
  cvt_kernel<<<512, 256, 0, stream>>>(Wq, wbf, 262144);
  cvt_kernel<<<512, 256, 0, stream>>>(Wk, wbf + 1048576, 262144);
  cvt_kernel<<<512, 256, 0, stream>>>(Wv, wbf + 2097152, 262144);
  cvt_kernel<<<512, 256, 0, stream>>>(Wp, wbf + 3145728, 262144);

  proj_qkv<<<dim3(128, 8, 3), 256, 0, stream>>>(xbf, wbf, bq, bk, bv, qbf, kbf, vtbf);
  attn_k<<<512, 512, 0, stream>>>(qbf, kbf, vtbf, xbf);
  proj_out<<<dim3(128, 8, 1), 256, 0, stream>>>(xbf, wbf + 3145728, bp, (float*)d_out);
}

// Round 2
// 396.072 us; speedup vs baseline: 2.3556x; 2.3556x over previous
//
#include <hip/hip_runtime.h>
#include <hip/hip_bf16.h>

#define DEVI __device__ __forceinline__

typedef float f32x4 __attribute__((ext_vector_type(4)));
typedef short bf16x8 __attribute__((ext_vector_type(8)));
typedef unsigned short u16x4 __attribute__((ext_vector_type(4)));

// B=16, H=16, N=1024, E=1024, D=64; M = B*N = 16384

DEVI unsigned short f2bf(float f) {
  union { float f; unsigned u; } v; v.f = f;
  unsigned r = v.u + 0x7fffu + ((v.u >> 16) & 1u);  // RNE
  return (unsigned short)(r >> 16);
}

DEVI float fexp2(float x) {
#if __has_builtin(__builtin_amdgcn_exp2f)
  return __builtin_amdgcn_exp2f(x);
#else
  return exp2f(x);
#endif
}

DEVI float frcp(float x) {
#if __has_builtin(__builtin_amdgcn_rcpf)
  return __builtin_amdgcn_rcpf(x);
#else
  return 1.0f / x;
#endif
}

DEVI unsigned cvtpk(float a, float b) {
  unsigned r;
  asm("v_cvt_pk_bf16_f32 %0, %1, %2" : "=v"(r) : "v"(a), "v"(b));
  return r;
}

DEVI void gload_lds16(const unsigned short* g, unsigned short* l) {
  __builtin_amdgcn_global_load_lds(
      (const __attribute__((address_space(1))) void*)g,
      (__attribute__((address_space(3))) void*)l, 16, 0, 0);
}

// ---------------- fp32 -> bf16 conversion ----------------
__global__ void cvt_kernel(const float* __restrict__ s, unsigned short* __restrict__ d, int n4) {
  int i = blockIdx.x * blockDim.x + threadIdx.x;
  const int st = gridDim.x * blockDim.x;
  for (; i < n4; i += st) {
    const float4 v = reinterpret_cast<const float4*>(s)[i];
    u16x4 o;
    o[0] = f2bf(v.x); o[1] = f2bf(v.y); o[2] = f2bf(v.z); o[3] = f2bf(v.w);
    reinterpret_cast<u16x4*>(d)[i] = o;
  }
}

// ---------------- shared 128x128x(K=1024) bf16 GEMM mainloop (B^T form) ----------------
DEVI void gemm_tile(const unsigned short* __restrict__ A,
                    const unsigned short* __restrict__ Bw,
                    int m0, int n0,
                    unsigned short* lsA, unsigned short* lsB,
                    f32x4 acc[4][4]) {
  const int tid = threadIdx.x;
  const int w = tid >> 6, l = tid & 63, lg = l >> 4, lr = l & 15;
  const int wr = w >> 1, wc = w & 1;
  for (int kt = 0; kt < 1024; kt += 64) {
#pragma unroll
    for (int i = 0; i < 4; i++) {
      const int c = i * 256 + tid;
      const int row = c >> 3, col = (c & 7) * 8;
      gload_lds16(&A[(m0 + row) * 1024 + kt + col], &lsA[(i * 256 + w * 64) * 8]);
      gload_lds16(&Bw[(n0 + row) * 1024 + kt + col], &lsB[(i * 256 + w * 64) * 8]);
    }
    __syncthreads();
#pragma unroll
    for (int ks = 0; ks < 2; ks++) {
      bf16x8 af[4], bf_[4];
#pragma unroll
      for (int fi = 0; fi < 4; fi++) af[fi] = *(const bf16x8*)&lsA[(wr * 64 + fi * 16 + lr) * 64 + ks * 32 + lg * 8];
#pragma unroll
      for (int fj = 0; fj < 4; fj++) bf_[fj] = *(const bf16x8*)&lsB[(wc * 64 + fj * 16 + lr) * 64 + ks * 32 + lg * 8];
#pragma unroll
      for (int fi = 0; fi < 4; fi++)
#pragma unroll
        for (int fj = 0; fj < 4; fj++)
          acc[fi][fj] = __builtin_amdgcn_mfma_f32_16x16x32_bf16(af[fi], bf_[fj], acc[fi][fj], 0, 0, 0);
    }
    __syncthreads();
  }
}

// ---------------- QKV projection with layout-specializing epilogues ----------------
// z=0: Q tiled fragments, pre-scaled by log2(e)
// z=1: K swapped [head][batch][n][d]
// z=2: V B-fragment tiles [b][h][kc][dt][lane][8]
__global__ __launch_bounds__(256, 2) void proj_qkv(
    const unsigned short* __restrict__ X, const unsigned short* __restrict__ W3,
    const float* __restrict__ bq, const float* __restrict__ bk, const float* __restrict__ bv,
    unsigned short* __restrict__ outq, unsigned short* __restrict__ outk, unsigned short* __restrict__ outv) {
  __shared__ unsigned short lsA[128 * 64];
  __shared__ unsigned short lsB[128 * 64];
  const int z = blockIdx.z;
  const int m0 = blockIdx.x * 128, n0 = blockIdx.y * 128;
  const unsigned short* Bw = W3 + z * 1048576;
  f32x4 acc[4][4];
  const f32x4 z4 = {0.f, 0.f, 0.f, 0.f};
#pragma unroll
  for (int i = 0; i < 4; i++)
#pragma unroll
    for (int j = 0; j < 4; j++) acc[i][j] = z4;
  gemm_tile(X, Bw, m0, n0, lsA, lsB, acc);

  const int tid = threadIdx.x;
  const int w = tid >> 6, l = tid & 63, lg = l >> 4, lr = l & 15, wr = w >> 1, wc = w & 1;
  const float* bias = (z == 0) ? bq : ((z == 1) ? bk : bv);
  const float SC = 1.4426950408889634f;  // log2(e), folded into Q
#pragma unroll
  for (int fi = 0; fi < 4; fi++) {
    const int mb = m0 + wr * 64 + fi * 16 + lg * 4;
#pragma unroll
    for (int fj = 0; fj < 4; fj++) {
      const int ncol = n0 + wc * 64 + fj * 16 + lr;
      const float bsv = bias[ncol];
      const int h = ncol >> 6, d = ncol & 63;
      if (z == 0) {
        const int ks = d >> 5, lgq = (d >> 3) & 3, eq = d & 7;
#pragma unroll
        for (int r = 0; r < 4; r++) {
          const int m = mb + r;
          const int bb = m >> 10, nr = m & 1023;
          const int nt = nr >> 4, lrq = nr & 15;
          const int idx = (((bb * 64 + nt) * 32 + h * 2 + ks) * 64 + lgq * 16 + lrq) * 8 + eq;
          outq[idx] = f2bf((acc[fi][fj][r] + bsv) * SC);
        }
      } else if (z == 1) {
#pragma unroll
        for (int r = 0; r < 4; r++) {
          const int m = mb + r;
          outk[((h * 16 + (m >> 10)) * 1024 + (m & 1023)) * 64 + d] = f2bf(acc[fi][fj][r] + bsv);
        }
      } else {
        const int dt = d >> 4, lrv = d & 15;
        const int bb = mb >> 10, n = mb & 1023;
        const int kc = n >> 5, lgv = (n >> 3) & 3, ev = n & 7;
        u16x4 pk;
#pragma unroll
        for (int r = 0; r < 4; r++) pk[r] = f2bf(acc[fi][fj][r] + bsv);
        const int idx0 = ((((bb * 16 + h) * 32 + kc) * 4 + dt) * 64 + lgv * 16 + lrv) * 8 + ev;
        *(u16x4*)&outv[idx0] = pk;
      }
    }
  }
}

// ---------------- output projection (fp32 out + bias) ----------------
__global__ __launch_bounds__(256, 2) void proj_out(
    const unsigned short* __restrict__ A, const unsigned short* __restrict__ Wp,
    const float* __restrict__ bias, float* __restrict__ out) {
  __shared__ unsigned short lsA[128 * 64];
  __shared__ unsigned short lsB[128 * 64];
  const int m0 = blockIdx.x * 128, n0 = blockIdx.y * 128;
  f32x4 acc[4][4];
  const f32x4 z4 = {0.f, 0.f, 0.f, 0.f};
#pragma unroll
  for (int i = 0; i < 4; i++)
#pragma unroll
    for (int j = 0; j < 4; j++) acc[i][j] = z4;
  gemm_tile(A, Wp, m0, n0, lsA, lsB, acc);
  const int tid = threadIdx.x;
  const int w = tid >> 6, l = tid & 63, lg = l >> 4, lr = l & 15, wr = w >> 1, wc = w & 1;
#pragma unroll
  for (int fi = 0; fi < 4; fi++) {
    const int mb = m0 + wr * 64 + fi * 16 + lg * 4;
#pragma unroll
    for (int fj = 0; fj < 4; fj++) {
      const int ncol = n0 + wc * 64 + fj * 16 + lr;
      const float bsv = bias[ncol];
#pragma unroll
      for (int r = 0; r < 4; r++) out[(mb + r) * 1024 + ncol] = acc[fi][fj][r] + bsv;
    }
  }
}

// ---------------- fused attention v2 ----------------
// grid: b(16) x qtile32(32). 8 waves/block. Per k-block of 64:
//   A0/A1: energy^T (mfma(K,Q)) for h-halves, K LDS-staged (gload_lds, swizzled src),
//          Q JIT from pre-tiled fragments, exp2 in-place (Q pre-scaled by log2 e).
//   softmax over h lane-local (4 consecutive k per lane via swapped operands).
//   att -> LDS (cvt_pk + ds_write_b64, XOR-swizzled).
//   B: PV, wave owns h-pair, V from pre-tiled fragments; next K-lo staged under B.
__global__ __launch_bounds__(512, 2) void attn2(
    const unsigned short* __restrict__ Q2,  // tiled frags
    const unsigned short* __restrict__ K,   // [head][batch][n][64]
    const unsigned short* __restrict__ VT2, // tiled frags
    unsigned short* __restrict__ O) {       // [16][1024][1024] natural
  __shared__ unsigned short kbuf[32768];  // 64 KB: K h-lo
  __shared__ unsigned short abuf[32768];  // 64 KB: K h-hi, then att

  const int tid = threadIdx.x;
  const int w = tid >> 6, l = tid & 63;
  const int lr = l & 15, lg = l >> 4;
  const int b = blockIdx.x >> 5, qt32 = blockIdx.x & 31;
  const int qh = w >> 2, ksub = w & 3;

  // K staging constants: row-within-wave + source-swizzled chunk
  const int kkl = l >> 3;
  const int cc = (l & 7) ^ kkl;
  const unsigned short* kbase = K + b * 1048576 + (w * 8 + kkl) * 64 + cc * 8;
  unsigned short* kdst0 = kbuf + w * 512;  // + r*4096 elems per round
  unsigned short* adst0 = abuf + w * 512;

  // K-fragment ds_read offsets (bytes)
  const int kk = ksub * 16 + lr;
  const int kv0 = kk * 128 + ((lg ^ (kk & 7)) << 4);
  const int kv1 = kv0 ^ 64;

  // Q fragment pointer (per-lane)
  const char* qb = (const char*)Q2 + (size_t)((b * 64 + qt32 * 2 + qh) * 32) * 1024 + l * 16;

  // att write offsets
  const int qwb = qh * 16 + lr;
  const int wswz = (qwb & 7) << 3;
  const int wbyte = qwb * 128 + (((ksub * 16 + lg * 4) ^ wswz) << 1);

  const f32x4 z4 = {0.f, 0.f, 0.f, 0.f};
  f32x4 oacc[2][2][4];
#pragma unroll
  for (int a = 0; a < 2; a++)
#pragma unroll
    for (int c = 0; c < 2; c++)
#pragma unroll
      for (int d = 0; d < 4; d++) oacc[a][c][d] = z4;

  // prologue: stage K-lo for kb0=0
#pragma unroll
  for (int r = 0; r < 8; r++) gload_lds16(kbase + r * 65536, kdst0 + r * 4096);
  __syncthreads();

  for (int kb0 = 0; kb0 < 1024; kb0 += 64) {
    f32x4 e[16];
    // ---- stage K-hi under A0 ----
#pragma unroll
    for (int r = 0; r < 8; r++)
      gload_lds16(kbase + (8 + r) * 65536 + kb0 * 64, adst0 + r * 4096);
    // ---- A0: h = 0..8 ----
#pragma unroll
    for (int j = 0; j < 8; j++) {
      bf16x8 q0 = *(const bf16x8*)(qb + (j * 2 + 0) * 1024);
      bf16x8 q1 = *(const bf16x8*)(qb + (j * 2 + 1) * 1024);
      bf16x8 k0 = *(const bf16x8*)((const char*)kbuf + j * 8192 + kv0);
      bf16x8 k1 = *(const bf16x8*)((const char*)kbuf + j * 8192 + kv1);
      f32x4 t = __builtin_amdgcn_mfma_f32_16x16x32_bf16(k0, q0, z4, 0, 0, 0);
      t = __builtin_amdgcn_mfma_f32_16x16x32_bf16(k1, q1, t, 0, 0, 0);
      t[0] = fexp2(t[0]); t[1] = fexp2(t[1]); t[2] = fexp2(t[2]); t[3] = fexp2(t[3]);
      e[j] = t;
    }
    __syncthreads();  // K-hi staged (drained), kbuf reads done
    // ---- A1: h = 8..16 ----
#pragma unroll
    for (int j = 0; j < 8; j++) {
      bf16x8 q0 = *(const bf16x8*)(qb + ((8 + j) * 2 + 0) * 1024);
      bf16x8 q1 = *(const bf16x8*)(qb + ((8 + j) * 2 + 1) * 1024);
      bf16x8 k0 = *(const bf16x8*)((const char*)abuf + j * 8192 + kv0);
      bf16x8 k1 = *(const bf16x8*)((const char*)abuf + j * 8192 + kv1);
      f32x4 t = __builtin_amdgcn_mfma_f32_16x16x32_bf16(k0, q0, z4, 0, 0, 0);
      t = __builtin_amdgcn_mfma_f32_16x16x32_bf16(k1, q1, t, 0, 0, 0);
      t[0] = fexp2(t[0]); t[1] = fexp2(t[1]); t[2] = fexp2(t[2]); t[3] = fexp2(t[3]);
      e[8 + j] = t;
    }
    // ---- softmax over h (lane-local; 4 k-slots per lane) ----
    f32x4 s = e[0];
#pragma unroll
    for (int h = 1; h < 16; h++) s += e[h];
    f32x4 inv;
    inv[0] = frcp(s[0]) * 0.03125f;
    inv[1] = frcp(s[1]) * 0.03125f;
    inv[2] = frcp(s[2]) * 0.03125f;
    inv[3] = frcp(s[3]) * 0.03125f;
    __syncthreads();  // all abuf (K-hi) reads done
#pragma unroll
    for (int h = 0; h < 16; h++) {
      f32x4 v = e[h] * inv;
      uint2 pk;
      pk.x = cvtpk(v[0], v[1]);
      pk.y = cvtpk(v[2], v[3]);
      *(uint2*)((char*)abuf + h * 4096 + wbyte) = pk;
    }
    __syncthreads();  // att visible
    // ---- B: PV (wave owns h-pair) + stage next K-lo ----
    const int kbn = (kb0 + 64) & 1023;
#pragma unroll
    for (int r = 0; r < 8; r++)
      gload_lds16(kbase + r * 65536 + kbn * 64, kdst0 + r * 4096);
    const int kc0 = kb0 >> 5;
#pragma unroll
    for (int hh = 0; hh < 2; hh++) {
      const int h = w * 2 + hh;
      const char* vbp = (const char*)VT2 + (size_t)(((b * 16 + h) * 32 + kc0) * 4) * 1024 + l * 16;
      bf16x8 vb[2][4];
#pragma unroll
      for (int kst = 0; kst < 2; kst++)
#pragma unroll
        for (int dt = 0; dt < 4; dt++)
          vb[kst][dt] = *(const bf16x8*)(vbp + (kst * 4 + dt) * 1024);
      bf16x8 pa[2][2];
#pragma unroll
      for (int qt = 0; qt < 2; qt++)
#pragma unroll
        for (int kst = 0; kst < 2; kst++)
          pa[qt][kst] = *(const bf16x8*)((const char*)abuf + h * 4096 + qt * 2048 + lr * 128 +
                                         (((kst * 4 + lg) ^ (lr & 7)) << 4));
#pragma unroll
      for (int qt = 0; qt < 2; qt++)
#pragma unroll
        for (int kst = 0; kst < 2; kst++)
#pragma unroll
          for (int dt = 0; dt < 4; dt++)
            oacc[hh][qt][dt] = __builtin_amdgcn_mfma_f32_16x16x32_bf16(pa[qt][kst], vb[kst][dt], oacc[hh][qt][dt], 0, 0, 0);
    }
    __syncthreads();  // att reads done; next K-lo staged (drained)
  }

  // ---- epilogue: O natural [b][n][e] ----
#pragma unroll
  for (int hh = 0; hh < 2; hh++) {
    const int h = w * 2 + hh;
#pragma unroll
    for (int qt = 0; qt < 2; qt++)
#pragma unroll
      for (int dt = 0; dt < 4; dt++)
#pragma unroll
        for (int r = 0; r < 4; r++) {
          const int n = qt32 * 32 + qt * 16 + lg * 4 + r;
          O[(size_t)(b * 1024 + n) * 1024 + h * 64 + dt * 16 + lr] = f2bf(oacc[hh][qt][dt][r]);
        }
  }
}

extern "C" void kernel_launch(void* const* d_in, const int* in_sizes, int n_in,
                              void* d_out, int out_size, void* d_ws, size_t ws_size,
                              hipStream_t stream) {
  const float* x  = (const float*)d_in[0];
  const float* Wq = (const float*)d_in[1];
  const float* bq = (const float*)d_in[2];
  const float* Wk = (const float*)d_in[3];
  const float* bk = (const float*)d_in[4];
  const float* Wv = (const float*)d_in[5];
  const float* bv = (const float*)d_in[6];
  const float* Wp = (const float*)d_in[7];
  const float* bp = (const float*)d_in[8];

  char* ws = (char*)d_ws;
  unsigned short* xbf  = (unsigned short*)(ws);              // 32 MiB; reused for O after attention
  unsigned short* qbf  = (unsigned short*)(ws + 33554432);   // Q2 fragment tiles
  unsigned short* kbf  = (unsigned short*)(ws + 67108864);   // K [head][batch][n][d]
  unsigned short* vtbf = (unsigned short*)(ws + 100663296);  // VT2 fragment tiles
  unsigned short* wbf  = (unsigned short*)(ws + 134217728);  // Wq,Wk,Wv,Wp bf16 (4 x 2 MiB)

  cvt_kernel<<<2048, 256, 0, stream>>>(x, xbf, 4194304);
  cvt_kernel<<<512, 256, 0, stream>>>(Wq, wbf, 262144);
  cvt_kernel<<<512, 256, 0, stream>>>(Wk, wbf + 1048576, 262144);
  cvt_kernel<<<512, 256, 0, stream>>>(Wv, wbf + 2097152, 262144);
  cvt_kernel<<<512, 256, 0, stream>>>(Wp, wbf + 3145728, 262144);

  proj_qkv<<<dim3(128, 8, 3), 256, 0, stream>>>(xbf, wbf, bq, bk, bv, qbf, kbf, vtbf);
  attn2<<<512, 512, 0, stream>>>(qbf, kbf, vtbf, xbf);
  proj_out<<<dim3(128, 8, 1), 256, 0, stream>>>(xbf, wbf + 3145728, bp, (float*)d_out);
}

// Round 3
// 366.022 us; speedup vs baseline: 2.5490x; 1.0821x over previous
//
#include <hip/hip_runtime.h>
#include <hip/hip_bf16.h>

#define DEVI __device__ __forceinline__

typedef float f32x4 __attribute__((ext_vector_type(4)));
typedef short bf16x8 __attribute__((ext_vector_type(8)));
typedef unsigned short u16x4 __attribute__((ext_vector_type(4)));

// B=16, H=16, N=1024, E=1024, D=64; M = B*N = 16384

DEVI unsigned short f2bf(float f) {
  union { float f; unsigned u; } v; v.f = f;
  unsigned r = v.u + 0x7fffu + ((v.u >> 16) & 1u);  // RNE
  return (unsigned short)(r >> 16);
}

DEVI float fexp2(float x) {
#if __has_builtin(__builtin_amdgcn_exp2f)
  return __builtin_amdgcn_exp2f(x);
#else
  return exp2f(x);
#endif
}

DEVI float frcp(float x) {
#if __has_builtin(__builtin_amdgcn_rcpf)
  return __builtin_amdgcn_rcpf(x);
#else
  return 1.0f / x;
#endif
}

DEVI unsigned cvtpk(float a, float b) {
  unsigned r;
  asm("v_cvt_pk_bf16_f32 %0, %1, %2" : "=v"(r) : "v"(a), "v"(b));
  return r;
}

DEVI void gload_lds16(const unsigned short* g, unsigned short* l) {
  __builtin_amdgcn_global_load_lds(
      (const __attribute__((address_space(1))) void*)g,
      (__attribute__((address_space(3))) void*)l, 16, 0, 0);
}

// ---------------- fp32 -> bf16 conversion ----------------
__global__ void cvt_kernel(const float* __restrict__ s, unsigned short* __restrict__ d, int n4) {
  int i = blockIdx.x * blockDim.x + threadIdx.x;
  const int st = gridDim.x * blockDim.x;
  for (; i < n4; i += st) {
    const float4 v = reinterpret_cast<const float4*>(s)[i];
    u16x4 o;
    o[0] = f2bf(v.x); o[1] = f2bf(v.y); o[2] = f2bf(v.z); o[3] = f2bf(v.w);
    reinterpret_cast<u16x4*>(d)[i] = o;
  }
}

// ---------------- shared 128x128x(K=1024) bf16 GEMM mainloop (B^T form) ----------------
DEVI void gemm_tile(const unsigned short* __restrict__ A,
                    const unsigned short* __restrict__ Bw,
                    int m0, int n0,
                    unsigned short* lsA, unsigned short* lsB,
                    f32x4 acc[4][4]) {
  const int tid = threadIdx.x;
  const int w = tid >> 6, l = tid & 63, lg = l >> 4, lr = l & 15;
  const int wr = w >> 1, wc = w & 1;
  for (int kt = 0; kt < 1024; kt += 64) {
#pragma unroll
    for (int i = 0; i < 4; i++) {
      const int c = i * 256 + tid;
      const int row = c >> 3, col = (c & 7) * 8;
      gload_lds16(&A[(m0 + row) * 1024 + kt + col], &lsA[(i * 256 + w * 64) * 8]);
      gload_lds16(&Bw[(n0 + row) * 1024 + kt + col], &lsB[(i * 256 + w * 64) * 8]);
    }
    __syncthreads();
#pragma unroll
    for (int ks = 0; ks < 2; ks++) {
      bf16x8 af[4], bf_[4];
#pragma unroll
      for (int fi = 0; fi < 4; fi++) af[fi] = *(const bf16x8*)&lsA[(wr * 64 + fi * 16 + lr) * 64 + ks * 32 + lg * 8];
#pragma unroll
      for (int fj = 0; fj < 4; fj++) bf_[fj] = *(const bf16x8*)&lsB[(wc * 64 + fj * 16 + lr) * 64 + ks * 32 + lg * 8];
#pragma unroll
      for (int fi = 0; fi < 4; fi++)
#pragma unroll
        for (int fj = 0; fj < 4; fj++)
          acc[fi][fj] = __builtin_amdgcn_mfma_f32_16x16x32_bf16(af[fi], bf_[fj], acc[fi][fj], 0, 0, 0);
    }
    __syncthreads();
  }
}

// ---------------- QKV projection with layout-specializing epilogues ----------------
// z=0: Q energy-B-frag tiles [b][nt64][h*2+ks][lane][8], pre-scaled by log2(e)
// z=1: K energy-A-frag tiles [hp][kt64][h_lab16][ks2][lane][8]  (einsum's swapped K)
// z=2: V PV-B-frag tiles [b*16+h][kc32][dt4][lane][8]
__global__ __launch_bounds__(256, 2) void proj_qkv(
    const unsigned short* __restrict__ X, const unsigned short* __restrict__ W3,
    const float* __restrict__ bq, const float* __restrict__ bk, const float* __restrict__ bv,
    unsigned short* __restrict__ outq, unsigned short* __restrict__ outk, unsigned short* __restrict__ outv) {
  __shared__ unsigned short lsA[128 * 64];
  __shared__ unsigned short lsB[128 * 64];
  const int z = blockIdx.z;
  const int m0 = blockIdx.x * 128, n0 = blockIdx.y * 128;
  const unsigned short* Bw = W3 + z * 1048576;
  f32x4 acc[4][4];
  const f32x4 z4 = {0.f, 0.f, 0.f, 0.f};
#pragma unroll
  for (int i = 0; i < 4; i++)
#pragma unroll
    for (int j = 0; j < 4; j++) acc[i][j] = z4;
  gemm_tile(X, Bw, m0, n0, lsA, lsB, acc);

  const int tid = threadIdx.x;
  const int w = tid >> 6, l = tid & 63, lg = l >> 4, lr = l & 15, wr = w >> 1, wc = w & 1;
  const float* bias = (z == 0) ? bq : ((z == 1) ? bk : bv);
  const float SC = 1.4426950408889634f;  // log2(e), folded into Q
#pragma unroll
  for (int fi = 0; fi < 4; fi++) {
    const int mb = m0 + wr * 64 + fi * 16 + lg * 4;
#pragma unroll
    for (int fj = 0; fj < 4; fj++) {
      const int ncol = n0 + wc * 64 + fj * 16 + lr;
      const float bsv = bias[ncol];
      const int h = ncol >> 6, d = ncol & 63;
      if (z == 0) {
        const int ks = d >> 5, lgq = (d >> 3) & 3, eq = d & 7;
#pragma unroll
        for (int r = 0; r < 4; r++) {
          const int m = mb + r;
          const int bb = m >> 10, nr = m & 1023;
          const int nt = nr >> 4, lrq = nr & 15;
          const int idx = (((bb * 64 + nt) * 32 + h * 2 + ks) * 64 + lgq * 16 + lrq) * 8 + eq;
          outq[idx] = f2bf((acc[fi][fj][r] + bsv) * SC);
        }
      } else if (z == 1) {
        // energy A-frag: lane = ((d&31)>>3)*16 + (k&15), tile kt = k>>4, 32-chunk ks = d>>5
        const int ks = d >> 5, lhi = ((d >> 3) & 3) * 16, eq = d & 7;
#pragma unroll
        for (int r = 0; r < 4; r++) {
          const int m = mb + r;
          const int n = m & 1023, bx = m >> 10;  // n = k-position, bx = einsum h-label
          const int lane = lhi + (n & 15);
          const int idx = ((((h * 64 + (n >> 4)) * 16 + bx) * 2 + ks) * 64 + lane) * 8 + eq;
          outk[idx] = f2bf(acc[fi][fj][r] + bsv);
        }
      } else {
        const int dt = d >> 4, lrv = d & 15;
        const int bb = mb >> 10, n = mb & 1023;
        const int kc = n >> 5, lgv = (n >> 3) & 3, ev = n & 7;
        u16x4 pk;
#pragma unroll
        for (int r = 0; r < 4; r++) pk[r] = f2bf(acc[fi][fj][r] + bsv);
        const int idx0 = ((((bb * 16 + h) * 32 + kc) * 4 + dt) * 64 + lgv * 16 + lrv) * 8 + ev;
        *(u16x4*)&outv[idx0] = pk;
      }
    }
  }
}

// ---------------- output projection (fp32 out + bias) ----------------
__global__ __launch_bounds__(256, 2) void proj_out(
    const unsigned short* __restrict__ A, const unsigned short* __restrict__ Wp,
    const float* __restrict__ bias, float* __restrict__ out) {
  __shared__ unsigned short lsA[128 * 64];
  __shared__ unsigned short lsB[128 * 64];
  const int m0 = blockIdx.x * 128, n0 = blockIdx.y * 128;
  f32x4 acc[4][4];
  const f32x4 z4 = {0.f, 0.f, 0.f, 0.f};
#pragma unroll
  for (int i = 0; i < 4; i++)
#pragma unroll
    for (int j = 0; j < 4; j++) acc[i][j] = z4;
  gemm_tile(A, Wp, m0, n0, lsA, lsB, acc);
  const int tid = threadIdx.x;
  const int w = tid >> 6, l = tid & 63, lg = l >> 4, lr = l & 15, wr = w >> 1, wc = w & 1;
#pragma unroll
  for (int fi = 0; fi < 4; fi++) {
    const int mb = m0 + wr * 64 + fi * 16 + lg * 4;
#pragma unroll
    for (int fj = 0; fj < 4; fj++) {
      const int ncol = n0 + wc * 64 + fj * 16 + lr;
      const float bsv = bias[ncol];
#pragma unroll
      for (int r = 0; r < 4; r++) out[(mb + r) * 1024 + ncol] = acc[fi][fj][r] + bsv;
    }
  }
}

// ---------------- fused attention v3 ----------------
// Q staged ONCE in LDS (iter-invariant); K/V read as pre-tiled global fragments
// (coalesced dwordx4 streams, vmcnt-pipelined, no stage-drain barriers).
// 2 barriers/iter (att write->read only). XCD-chunked block swizzle for K/V L2 locality.
__global__ __launch_bounds__(512, 2) void attn3(
    const unsigned short* __restrict__ Q2,  // [b][nt64][h*2+ks][lane][8]
    const unsigned short* __restrict__ K2,  // [hp][kt64][h_lab16][ks2][lane][8]
    const unsigned short* __restrict__ V2,  // [b*16+h][kc32][dt4][lane][8]
    unsigned short* __restrict__ O) {       // [16][1024][1024] natural
  __shared__ unsigned short qlds[32768];  // 64 KB Q fragments (loaded once)
  __shared__ unsigned short abuf[32768];  // 64 KB att [h][q32][k64], XOR-swizzled

  const int tid = threadIdx.x;
  const int w = tid >> 6, l = tid & 63;
  const int lr = l & 15, lg = l >> 4;
  // XCD-chunked swizzle: 512 wgs, 8 chunks of 64 -> each XCD owns 2 batches
  const int bid = blockIdx.x;
  const int swz = (bid & 7) * 64 + (bid >> 3);
  const int b = swz >> 5, qt32 = swz & 31;
  const int qh = w >> 2, ksub = w & 3;

  // ---- stage Q once: 64 KB contiguous chunk ----
  {
    const unsigned short* qsrc = Q2 + (size_t)(b * 64 + qt32 * 2) * 16384 + (w * 64 + l) * 8;
    unsigned short* qdst = qlds + w * 512;
#pragma unroll
    for (int r = 0; r < 8; r++)
      gload_lds16(qsrc + r * 4096, qdst + r * 4096);
  }

  // att write offsets (same as verified attn2)
  const int qwb = qh * 16 + lr;
  const int wswz = (qwb & 7) << 3;
  const int wbyte = qwb * 128 + (((ksub * 16 + lg * 4) ^ wswz) << 1);

  const f32x4 z4 = {0.f, 0.f, 0.f, 0.f};
  f32x4 oacc[2][2][4];
#pragma unroll
  for (int a = 0; a < 2; a++)
#pragma unroll
    for (int c = 0; c < 2; c++)
#pragma unroll
      for (int d = 0; d < 4; d++) oacc[a][c][d] = z4;

  __syncthreads();  // Q staged

  for (int it = 0; it < 16; it++) {
    // anti-LICM: keep Q LDS reads inside the loop (byte-offset opaque, AS3 preserved)
    int qo = 0;
    asm volatile("" : "+v"(qo));
    const int kt = it * 4 + ksub;
    const unsigned short* kp = K2 + (size_t)(b * 64 + kt) * 16384 + l * 8;

    // ---- energy: all 16 heads (K global frags + Q LDS frags) ----
    f32x4 e[16];
#pragma unroll
    for (int h = 0; h < 16; h++) {
      bf16x8 q0 = *(const bf16x8*)((const char*)qlds + qo + (qh * 32 + h * 2 + 0) * 1024 + l * 16);
      bf16x8 q1 = *(const bf16x8*)((const char*)qlds + qo + (qh * 32 + h * 2 + 1) * 1024 + l * 16);
      bf16x8 k0 = *(const bf16x8*)(kp + (h * 2 + 0) * 512);
      bf16x8 k1 = *(const bf16x8*)(kp + (h * 2 + 1) * 512);
      f32x4 t = __builtin_amdgcn_mfma_f32_16x16x32_bf16(k0, q0, z4, 0, 0, 0);
      t = __builtin_amdgcn_mfma_f32_16x16x32_bf16(k1, q1, t, 0, 0, 0);
      t[0] = fexp2(t[0]); t[1] = fexp2(t[1]); t[2] = fexp2(t[2]); t[3] = fexp2(t[3]);
      e[h] = t;
    }
    // ---- softmax over h (lane-local) ----
    f32x4 s = e[0];
#pragma unroll
    for (int h = 1; h < 16; h++) s += e[h];
    f32x4 inv;
    inv[0] = frcp(s[0]) * 0.03125f;
    inv[1] = frcp(s[1]) * 0.03125f;
    inv[2] = frcp(s[2]) * 0.03125f;
    inv[3] = frcp(s[3]) * 0.03125f;
    __syncthreads();  // prev-iter PV att reads complete
#pragma unroll
    for (int h = 0; h < 16; h++) {
      f32x4 v = e[h] * inv;
      uint2 pk;
      pk.x = cvtpk(v[0], v[1]);
      pk.y = cvtpk(v[2], v[3]);
      *(uint2*)((char*)abuf + h * 4096 + wbyte) = pk;
    }
    __syncthreads();  // att visible
    // ---- PV: wave owns h-pair; V global frags ----
    const int kc0 = it * 2;
#pragma unroll
    for (int hh = 0; hh < 2; hh++) {
      const int h = w * 2 + hh;
      const char* vbp = (const char*)V2 + (size_t)(((b * 16 + h) * 32 + kc0) * 4) * 1024 + l * 16;
      bf16x8 vb[2][4];
#pragma unroll
      for (int kst = 0; kst < 2; kst++)
#pragma unroll
        for (int dt = 0; dt < 4; dt++)
          vb[kst][dt] = *(const bf16x8*)(vbp + (kst * 4 + dt) * 1024);
      bf16x8 pa[2][2];
#pragma unroll
      for (int qt = 0; qt < 2; qt++)
#pragma unroll
        for (int kst = 0; kst < 2; kst++)
          pa[qt][kst] = *(const bf16x8*)((const char*)abuf + h * 4096 + qt * 2048 + lr * 128 +
                                         (((kst * 4 + lg) ^ (lr & 7)) << 4));
#pragma unroll
      for (int qt = 0; qt < 2; qt++)
#pragma unroll
        for (int kst = 0; kst < 2; kst++)
#pragma unroll
          for (int dt = 0; dt < 4; dt++)
            oacc[hh][qt][dt] = __builtin_amdgcn_mfma_f32_16x16x32_bf16(pa[qt][kst], vb[kst][dt], oacc[hh][qt][dt], 0, 0, 0);
    }
  }

  // ---- epilogue: O natural [b][n][e] ----
#pragma unroll
  for (int hh = 0; hh < 2; hh++) {
    const int h = w * 2 + hh;
#pragma unroll
    for (int qt = 0; qt < 2; qt++)
#pragma unroll
      for (int dt = 0; dt < 4; dt++)
#pragma unroll
        for (int r = 0; r < 4; r++) {
          const int n = qt32 * 32 + qt * 16 + lg * 4 + r;
          O[(size_t)(b * 1024 + n) * 1024 + h * 64 + dt * 16 + lr] = f2bf(oacc[hh][qt][dt][r]);
        }
  }
}

extern "C" void kernel_launch(void* const* d_in, const int* in_sizes, int n_in,
                              void* d_out, int out_size, void* d_ws, size_t ws_size,
                              hipStream_t stream) {
  const float* x  = (const float*)d_in[0];
  const float* Wq = (const float*)d_in[1];
  const float* bq = (const float*)d_in[2];
  const float* Wk = (const float*)d_in[3];
  const float* bk = (const float*)d_in[4];
  const float* Wv = (const float*)d_in[5];
  const float* bv = (const float*)d_in[6];
  const float* Wp = (const float*)d_in[7];
  const float* bp = (const float*)d_in[8];

  char* ws = (char*)d_ws;
  unsigned short* xbf  = (unsigned short*)(ws);              // 32 MiB; reused for O after attention
  unsigned short* qbf  = (unsigned short*)(ws + 33554432);   // Q2 fragment tiles
  unsigned short* kbf  = (unsigned short*)(ws + 67108864);   // K2 fragment tiles
  unsigned short* vtbf = (unsigned short*)(ws + 100663296);  // V2 fragment tiles
  unsigned short* wbf  = (unsigned short*)(ws + 134217728);  // Wq,Wk,Wv,Wp bf16 (4 x 2 MiB)

  cvt_kernel<<<2048, 256, 0, stream>>>(x, xbf, 4194304);
  cvt_kernel<<<512, 256, 0, stream>>>(Wq, wbf, 262144);
  cvt_kernel<<<512, 256, 0, stream>>>(Wk, wbf + 1048576, 262144);
  cvt_kernel<<<512, 256, 0, stream>>>(Wv, wbf + 2097152, 262144);
  cvt_kernel<<<512, 256, 0, stream>>>(Wp, wbf + 3145728, 262144);

  proj_qkv<<<dim3(128, 8, 3), 256, 0, stream>>>(xbf, wbf, bq, bk, bv, qbf, kbf, vtbf);
  attn3<<<512, 512, 0, stream>>>(qbf, kbf, vtbf, xbf);
  proj_out<<<dim3(128, 8, 1), 256, 0, stream>>>(xbf, wbf + 3145728, bp, (float*)d_out);
}

// Round 4
// 352.123 us; speedup vs baseline: 2.6496x; 1.0395x over previous
//
#include <hip/hip_runtime.h>
#include <hip/hip_bf16.h>

#define DEVI __device__ __forceinline__

typedef float f32x4 __attribute__((ext_vector_type(4)));
typedef short bf16x8 __attribute__((ext_vector_type(8)));
typedef unsigned short u16x4 __attribute__((ext_vector_type(4)));

// B=16, H=16, N=1024, E=1024, D=64; M = B*N = 16384

DEVI unsigned short f2bf(float f) {
  union { float f; unsigned u; } v; v.f = f;
  unsigned r = v.u + 0x7fffu + ((v.u >> 16) & 1u);  // RNE
  return (unsigned short)(r >> 16);
}

DEVI float fexp2(float x) {
#if __has_builtin(__builtin_amdgcn_exp2f)
  return __builtin_amdgcn_exp2f(x);
#else
  return exp2f(x);
#endif
}

DEVI float frcp(float x) {
#if __has_builtin(__builtin_amdgcn_rcpf)
  return __builtin_amdgcn_rcpf(x);
#else
  return 1.0f / x;
#endif
}

DEVI unsigned cvtpk(float a, float b) {
  unsigned r;
  asm("v_cvt_pk_bf16_f32 %0, %1, %2" : "=v"(r) : "v"(a), "v"(b));
  return r;
}

DEVI void gload_lds16(const unsigned short* g, unsigned short* l) {
  __builtin_amdgcn_global_load_lds(
      (const __attribute__((address_space(1))) void*)g,
      (__attribute__((address_space(3))) void*)l, 16, 0, 0);
}

// ---------------- fp32 -> bf16 conversion ----------------
__global__ void cvt_kernel(const float* __restrict__ s, unsigned short* __restrict__ d, int n4) {
  int i = blockIdx.x * blockDim.x + threadIdx.x;
  const int st = gridDim.x * blockDim.x;
  for (; i < n4; i += st) {
    const float4 v = reinterpret_cast<const float4*>(s)[i];
    u16x4 o;
    o[0] = f2bf(v.x); o[1] = f2bf(v.y); o[2] = f2bf(v.z); o[3] = f2bf(v.w);
    reinterpret_cast<u16x4*>(d)[i] = o;
  }
}

// ---------------- shared 128x128x(K=1024) bf16 GEMM mainloop (B^T form) ----------------
DEVI void gemm_tile(const unsigned short* __restrict__ A,
                    const unsigned short* __restrict__ Bw,
                    int m0, int n0,
                    unsigned short* lsA, unsigned short* lsB,
                    f32x4 acc[4][4]) {
  const int tid = threadIdx.x;
  const int w = tid >> 6, l = tid & 63, lg = l >> 4, lr = l & 15;
  const int wr = w >> 1, wc = w & 1;
  for (int kt = 0; kt < 1024; kt += 64) {
#pragma unroll
    for (int i = 0; i < 4; i++) {
      const int c = i * 256 + tid;
      const int row = c >> 3, col = (c & 7) * 8;
      gload_lds16(&A[(m0 + row) * 1024 + kt + col], &lsA[(i * 256 + w * 64) * 8]);
      gload_lds16(&Bw[(n0 + row) * 1024 + kt + col], &lsB[(i * 256 + w * 64) * 8]);
    }
    __syncthreads();
#pragma unroll
    for (int ks = 0; ks < 2; ks++) {
      bf16x8 af[4], bf_[4];
#pragma unroll
      for (int fi = 0; fi < 4; fi++) af[fi] = *(const bf16x8*)&lsA[(wr * 64 + fi * 16 + lr) * 64 + ks * 32 + lg * 8];
#pragma unroll
      for (int fj = 0; fj < 4; fj++) bf_[fj] = *(const bf16x8*)&lsB[(wc * 64 + fj * 16 + lr) * 64 + ks * 32 + lg * 8];
#pragma unroll
      for (int fi = 0; fi < 4; fi++)
#pragma unroll
        for (int fj = 0; fj < 4; fj++)
          acc[fi][fj] = __builtin_amdgcn_mfma_f32_16x16x32_bf16(af[fi], bf_[fj], acc[fi][fj], 0, 0, 0);
    }
    __syncthreads();
  }
}

// ---------------- QKV projection with layout-specializing epilogues ----------------
// z=0: Q energy-B-frag tiles [b][nt64][h*2+ks][lane][8], pre-scaled by log2(e)
// z=1: K energy-A-frag tiles [hp][kt64][h_lab16][ks2][lane][8]  (einsum's swapped K)
// z=2: V PV-B-frag tiles [b*16+h][kc32][dt4][lane][8]
__global__ __launch_bounds__(256, 2) void proj_qkv(
    const unsigned short* __restrict__ X, const unsigned short* __restrict__ W3,
    const float* __restrict__ bq, const float* __restrict__ bk, const float* __restrict__ bv,
    unsigned short* __restrict__ outq, unsigned short* __restrict__ outk, unsigned short* __restrict__ outv) {
  __shared__ unsigned short lsA[128 * 64];
  __shared__ unsigned short lsB[128 * 64];
  const int z = blockIdx.z;
  const int m0 = blockIdx.x * 128, n0 = blockIdx.y * 128;
  const unsigned short* Bw = W3 + z * 1048576;
  f32x4 acc[4][4];
  const f32x4 z4 = {0.f, 0.f, 0.f, 0.f};
#pragma unroll
  for (int i = 0; i < 4; i++)
#pragma unroll
    for (int j = 0; j < 4; j++) acc[i][j] = z4;
  gemm_tile(X, Bw, m0, n0, lsA, lsB, acc);

  const int tid = threadIdx.x;
  const int w = tid >> 6, l = tid & 63, lg = l >> 4, lr = l & 15, wr = w >> 1, wc = w & 1;
  const float* bias = (z == 0) ? bq : ((z == 1) ? bk : bv);
  const float SC = 1.4426950408889634f;  // log2(e), folded into Q
#pragma unroll
  for (int fi = 0; fi < 4; fi++) {
    const int mb = m0 + wr * 64 + fi * 16 + lg * 4;
#pragma unroll
    for (int fj = 0; fj < 4; fj++) {
      const int ncol = n0 + wc * 64 + fj * 16 + lr;
      const float bsv = bias[ncol];
      const int h = ncol >> 6, d = ncol & 63;
      if (z == 0) {
        const int ks = d >> 5, lgq = (d >> 3) & 3, eq = d & 7;
#pragma unroll
        for (int r = 0; r < 4; r++) {
          const int m = mb + r;
          const int bb = m >> 10, nr = m & 1023;
          const int nt = nr >> 4, lrq = nr & 15;
          const int idx = (((bb * 64 + nt) * 32 + h * 2 + ks) * 64 + lgq * 16 + lrq) * 8 + eq;
          outq[idx] = f2bf((acc[fi][fj][r] + bsv) * SC);
        }
      } else if (z == 1) {
        // energy A-frag: lane = ((d&31)>>3)*16 + (k&15), tile kt = k>>4, 32-chunk ks = d>>5
        const int ks = d >> 5, lhi = ((d >> 3) & 3) * 16, eq = d & 7;
#pragma unroll
        for (int r = 0; r < 4; r++) {
          const int m = mb + r;
          const int n = m & 1023, bx = m >> 10;  // n = k-position, bx = einsum h-label
          const int lane = lhi + (n & 15);
          const int idx = ((((h * 64 + (n >> 4)) * 16 + bx) * 2 + ks) * 64 + lane) * 8 + eq;
          outk[idx] = f2bf(acc[fi][fj][r] + bsv);
        }
      } else {
        const int dt = d >> 4, lrv = d & 15;
        const int bb = mb >> 10, n = mb & 1023;
        const int kc = n >> 5, lgv = (n >> 3) & 3, ev = n & 7;
        u16x4 pk;
#pragma unroll
        for (int r = 0; r < 4; r++) pk[r] = f2bf(acc[fi][fj][r] + bsv);
        const int idx0 = ((((bb * 16 + h) * 32 + kc) * 4 + dt) * 64 + lgv * 16 + lrv) * 8 + ev;
        *(u16x4*)&outv[idx0] = pk;
      }
    }
  }
}

// ---------------- output projection (fp32 out + bias) ----------------
__global__ __launch_bounds__(256, 2) void proj_out(
    const unsigned short* __restrict__ A, const unsigned short* __restrict__ Wp,
    const float* __restrict__ bias, float* __restrict__ out) {
  __shared__ unsigned short lsA[128 * 64];
  __shared__ unsigned short lsB[128 * 64];
  const int m0 = blockIdx.x * 128, n0 = blockIdx.y * 128;
  f32x4 acc[4][4];
  const f32x4 z4 = {0.f, 0.f, 0.f, 0.f};
#pragma unroll
  for (int i = 0; i < 4; i++)
#pragma unroll
    for (int j = 0; j < 4; j++) acc[i][j] = z4;
  gemm_tile(A, Wp, m0, n0, lsA, lsB, acc);
  const int tid = threadIdx.x;
  const int w = tid >> 6, l = tid & 63, lg = l >> 4, lr = l & 15, wr = w >> 1, wc = w & 1;
#pragma unroll
  for (int fi = 0; fi < 4; fi++) {
    const int mb = m0 + wr * 64 + fi * 16 + lg * 4;
#pragma unroll
    for (int fj = 0; fj < 4; fj++) {
      const int ncol = n0 + wc * 64 + fj * 16 + lr;
      const float bsv = bias[ncol];
#pragma unroll
      for (int r = 0; r < 4; r++) out[(mb + r) * 1024 + ncol] = acc[fi][fj][r] + bsv;
    }
  }
}

// ---------------- fused attention v4 ----------------
// 1024 thr, 16 waves = 4 ksub x 4 hq. Energy: wave computes its 4-h quarter for
// BOTH 16-q tiles (each K frag read by exactly ONE wave -> no dup L2 traffic).
// Softmax h-sum: 4-wave partial exchange via 32 KB region aliased into abuf.
// PV: wave owns h = w (one head). 4 barriers/iter, 128 KB LDS, 4 waves/SIMD.
__global__ __launch_bounds__(1024, 4) void attn4(
    const unsigned short* __restrict__ Q2,  // [b][nt64][h*2+ks][lane][8]
    const unsigned short* __restrict__ K2,  // [hp][kt64][h_lab16][ks2][lane][8]
    const unsigned short* __restrict__ V2,  // [b*16+h][kc32][dt4][lane][8]
    unsigned short* __restrict__ O) {       // [16][1024][1024] natural
  __shared__ unsigned short qlds[32768];  // 64 KB Q fragments (loaded once)
  __shared__ unsigned short abuf[32768];  // 64 KB att; first 32 KB doubles as sum-exchange

  const int tid = threadIdx.x;
  const int w = tid >> 6, l = tid & 63;
  const int lr = l & 15, lg = l >> 4;
  const int bid = blockIdx.x;
  const int swz = (bid & 7) * 64 + (bid >> 3);  // XCD-chunked
  const int b = swz >> 5, qt32 = swz & 31;
  const int ksub = w & 3, hq = w >> 2;  // energy role; PV role: h = w

  // ---- stage Q once: 64 KB contiguous ----
  {
    const unsigned short* qsrc = Q2 + (size_t)(b * 64 + qt32 * 2) * 16384 + tid * 8;
    unsigned short* qdst = qlds + tid * 8;
#pragma unroll
    for (int r = 0; r < 4; r++) gload_lds16(qsrc + r * 8192, qdst + r * 8192);
  }

  const int kpart = ksub * 16 + lg * 4;   // k-elem base of my 4 acc slots
  const int wswz = (lr & 7) << 3;

  const f32x4 z4 = {0.f, 0.f, 0.f, 0.f};
  f32x4 oacc[2][4];
#pragma unroll
  for (int qt = 0; qt < 2; qt++)
#pragma unroll
    for (int dt = 0; dt < 4; dt++) oacc[qt][dt] = z4;

  __syncthreads();  // Q staged

#pragma unroll 1
  for (int it = 0; it < 16; it++) {
    int qo = 0;
    asm volatile("" : "+v"(qo));  // keep Q LDS reads inside the loop
    const int kt = it * 4 + ksub;
    const unsigned short* kp = K2 + (size_t)(b * 64 + kt) * 16384 + l * 8;

    // ---- energy: my 4 heads x both q-tiles ----
    f32x4 e[4][2];
#pragma unroll
    for (int hl = 0; hl < 4; hl++) {
      const int h = hq * 4 + hl;
      bf16x8 k0 = *(const bf16x8*)(kp + (h * 2 + 0) * 512);
      bf16x8 k1 = *(const bf16x8*)(kp + (h * 2 + 1) * 512);
#pragma unroll
      for (int qh = 0; qh < 2; qh++) {
        bf16x8 q0 = *(const bf16x8*)((const char*)qlds + qo + (qh * 32 + h * 2 + 0) * 1024 + l * 16);
        bf16x8 q1 = *(const bf16x8*)((const char*)qlds + qo + (qh * 32 + h * 2 + 1) * 1024 + l * 16);
        f32x4 t = __builtin_amdgcn_mfma_f32_16x16x32_bf16(k0, q0, z4, 0, 0, 0);
        t = __builtin_amdgcn_mfma_f32_16x16x32_bf16(k1, q1, t, 0, 0, 0);
        t[0] = fexp2(t[0]); t[1] = fexp2(t[1]); t[2] = fexp2(t[2]); t[3] = fexp2(t[3]);
        e[hl][qh] = t;
      }
    }
    // ---- partial h-sums (my 4 heads) ----
    f32x4 s0 = (e[0][0] + e[1][0]) + (e[2][0] + e[3][0]);
    f32x4 s1 = (e[0][1] + e[1][1]) + (e[2][1] + e[3][1]);
    __syncthreads();  // [X] prev-iter PV att reads complete
    *(f32x4*)((char*)abuf + (((ksub * 4 + hq) * 2 + 0) * 64 + l) * 16) = s0;
    *(f32x4*)((char*)abuf + (((ksub * 4 + hq) * 2 + 1) * 64 + l) * 16) = s1;
    __syncthreads();  // [A] partials visible
#pragma unroll
    for (int p = 1; p < 4; p++) {
      const int hqp = hq ^ p;
      s0 += *(const f32x4*)((char*)abuf + (((ksub * 4 + hqp) * 2 + 0) * 64 + l) * 16);
      s1 += *(const f32x4*)((char*)abuf + (((ksub * 4 + hqp) * 2 + 1) * 64 + l) * 16);
    }
    f32x4 inv0, inv1;
    inv0[0] = frcp(s0[0]) * 0.03125f; inv0[1] = frcp(s0[1]) * 0.03125f;
    inv0[2] = frcp(s0[2]) * 0.03125f; inv0[3] = frcp(s0[3]) * 0.03125f;
    inv1[0] = frcp(s1[0]) * 0.03125f; inv1[1] = frcp(s1[1]) * 0.03125f;
    inv1[2] = frcp(s1[2]) * 0.03125f; inv1[3] = frcp(s1[3]) * 0.03125f;
    __syncthreads();  // [A2] partial reads done (att writes will overwrite region)
    // ---- att writes (my 4 heads x 2 q-tiles), XOR-swizzled bf16 ----
#pragma unroll
    for (int hl = 0; hl < 4; hl++) {
      const int h = hq * 4 + hl;
#pragma unroll
      for (int qh = 0; qh < 2; qh++) {
        f32x4 v = e[hl][qh] * (qh ? inv1 : inv0);
        uint2 pk;
        pk.x = cvtpk(v[0], v[1]);
        pk.y = cvtpk(v[2], v[3]);
        const int q = qh * 16 + lr;
        *(uint2*)((char*)abuf + h * 4096 + q * 128 + ((kpart ^ wswz) << 1)) = pk;
      }
    }
    __syncthreads();  // [B] att visible
    // ---- PV: wave owns h = w ----
    const int kc0 = it * 2;
    const char* vbp = (const char*)V2 + (size_t)(((b * 16 + w) * 32 + kc0) * 4) * 1024 + l * 16;
    bf16x8 vb[2][4];
#pragma unroll
    for (int kst = 0; kst < 2; kst++)
#pragma unroll
      for (int dt = 0; dt < 4; dt++)
        vb[kst][dt] = *(const bf16x8*)(vbp + (kst * 4 + dt) * 1024);
    bf16x8 pa[2][2];
#pragma unroll
    for (int qt = 0; qt < 2; qt++)
#pragma unroll
      for (int kst = 0; kst < 2; kst++)
        pa[qt][kst] = *(const bf16x8*)((const char*)abuf + w * 4096 + qt * 2048 + lr * 128 +
                                       (((kst * 4 + lg) ^ (lr & 7)) << 4));
#pragma unroll
    for (int qt = 0; qt < 2; qt++)
#pragma unroll
      for (int kst = 0; kst < 2; kst++)
#pragma unroll
        for (int dt = 0; dt < 4; dt++)
          oacc[qt][dt] = __builtin_amdgcn_mfma_f32_16x16x32_bf16(pa[qt][kst], vb[kst][dt], oacc[qt][dt], 0, 0, 0);
  }

  // ---- epilogue: O natural [b][n][e], my head h = w ----
#pragma unroll
  for (int qt = 0; qt < 2; qt++)
#pragma unroll
    for (int dt = 0; dt < 4; dt++)
#pragma unroll
      for (int r = 0; r < 4; r++) {
        const int n = qt32 * 32 + qt * 16 + lg * 4 + r;
        O[(size_t)(b * 1024 + n) * 1024 + w * 64 + dt * 16 + lr] = f2bf(oacc[qt][dt][r]);
      }
}

extern "C" void kernel_launch(void* const* d_in, const int* in_sizes, int n_in,
                              void* d_out, int out_size, void* d_ws, size_t ws_size,
                              hipStream_t stream) {
  const float* x  = (const float*)d_in[0];
  const float* Wq = (const float*)d_in[1];
  const float* bq = (const float*)d_in[2];
  const float* Wk = (const float*)d_in[3];
  const float* bk = (const float*)d_in[4];
  const float* Wv = (const float*)d_in[5];
  const float* bv = (const float*)d_in[6];
  const float* Wp = (const float*)d_in[7];
  const float* bp = (const float*)d_in[8];

  char* ws = (char*)d_ws;
  unsigned short* xbf  = (unsigned short*)(ws);              // 32 MiB; reused for O after attention
  unsigned short* qbf  = (unsigned short*)(ws + 33554432);   // Q2 fragment tiles
  unsigned short* kbf  = (unsigned short*)(ws + 67108864);   // K2 fragment tiles
  unsigned short* vtbf = (unsigned short*)(ws + 100663296);  // V2 fragment tiles
  unsigned short* wbf  = (unsigned short*)(ws + 134217728);  // Wq,Wk,Wv,Wp bf16 (4 x 2 MiB)

  cvt_kernel<<<2048, 256, 0, stream>>>(x, xbf, 4194304);
  cvt_kernel<<<512, 256, 0, stream>>>(Wq, wbf, 262144);
  cvt_kernel<<<512, 256, 0, stream>>>(Wk, wbf + 1048576, 262144);
  cvt_kernel<<<512, 256, 0, stream>>>(Wv, wbf + 2097152, 262144);
  cvt_kernel<<<512, 256, 0, stream>>>(Wp, wbf + 3145728, 262144);

  proj_qkv<<<dim3(128, 8, 3), 256, 0, stream>>>(xbf, wbf, bq, bk, bv, qbf, kbf, vtbf);
  attn4<<<512, 1024, 0, stream>>>(qbf, kbf, vtbf, xbf);
  proj_out<<<dim3(128, 8, 1), 256, 0, stream>>>(xbf, wbf + 3145728, bp, (float*)d_out);
}

// Round 5
// 350.254 us; speedup vs baseline: 2.6638x; 1.0053x over previous
//
#include <hip/hip_runtime.h>
#include <hip/hip_bf16.h>

#define DEVI __device__ __forceinline__

typedef float f32x4 __attribute__((ext_vector_type(4)));
typedef short bf16x8 __attribute__((ext_vector_type(8)));
typedef unsigned short u16x4 __attribute__((ext_vector_type(4)));

// B=16, H=16, N=1024, E=1024, D=64; M = B*N = 16384

DEVI unsigned short f2bf(float f) {
  union { float f; unsigned u; } v; v.f = f;
  unsigned r = v.u + 0x7fffu + ((v.u >> 16) & 1u);  // RNE
  return (unsigned short)(r >> 16);
}

DEVI float fexp2(float x) {
#if __has_builtin(__builtin_amdgcn_exp2f)
  return __builtin_amdgcn_exp2f(x);
#else
  return exp2f(x);
#endif
}

DEVI float frcp(float x) {
#if __has_builtin(__builtin_amdgcn_rcpf)
  return __builtin_amdgcn_rcpf(x);
#else
  return 1.0f / x;
#endif
}

DEVI unsigned cvtpk(float a, float b) {
  unsigned r;
  asm("v_cvt_pk_bf16_f32 %0, %1, %2" : "=v"(r) : "v"(a), "v"(b));
  return r;
}

DEVI void gload_lds16(const unsigned short* g, unsigned short* l) {
  __builtin_amdgcn_global_load_lds(
      (const __attribute__((address_space(1))) void*)g,
      (__attribute__((address_space(3))) void*)l, 16, 0, 0);
}

// workgroup barrier that does NOT drain vmcnt: LDS visibility only.
// Global loads (K/V prefetch) stay in flight across it.
DEVI void wg_barrier() {
  asm volatile("s_waitcnt lgkmcnt(0)" ::: "memory");
  __builtin_amdgcn_s_barrier();
  __builtin_amdgcn_sched_barrier(0);
}

// ---------------- fp32 -> bf16 conversion ----------------
__global__ void cvt_kernel(const float* __restrict__ s, unsigned short* __restrict__ d, int n4) {
  int i = blockIdx.x * blockDim.x + threadIdx.x;
  const int st = gridDim.x * blockDim.x;
  for (; i < n4; i += st) {
    const float4 v = reinterpret_cast<const float4*>(s)[i];
    u16x4 o;
    o[0] = f2bf(v.x); o[1] = f2bf(v.y); o[2] = f2bf(v.z); o[3] = f2bf(v.w);
    reinterpret_cast<u16x4*>(d)[i] = o;
  }
}

// ---------------- shared 128x128x(K=1024) bf16 GEMM mainloop (B^T form) ----------------
DEVI void gemm_tile(const unsigned short* __restrict__ A,
                    const unsigned short* __restrict__ Bw,
                    int m0, int n0,
                    unsigned short* lsA, unsigned short* lsB,
                    f32x4 acc[4][4]) {
  const int tid = threadIdx.x;
  const int w = tid >> 6, l = tid & 63, lg = l >> 4, lr = l & 15;
  const int wr = w >> 1, wc = w & 1;
  for (int kt = 0; kt < 1024; kt += 64) {
#pragma unroll
    for (int i = 0; i < 4; i++) {
      const int c = i * 256 + tid;
      const int row = c >> 3, col = (c & 7) * 8;
      gload_lds16(&A[(m0 + row) * 1024 + kt + col], &lsA[(i * 256 + w * 64) * 8]);
      gload_lds16(&Bw[(n0 + row) * 1024 + kt + col], &lsB[(i * 256 + w * 64) * 8]);
    }
    __syncthreads();
#pragma unroll
    for (int ks = 0; ks < 2; ks++) {
      bf16x8 af[4], bf_[4];
#pragma unroll
      for (int fi = 0; fi < 4; fi++) af[fi] = *(const bf16x8*)&lsA[(wr * 64 + fi * 16 + lr) * 64 + ks * 32 + lg * 8];
#pragma unroll
      for (int fj = 0; fj < 4; fj++) bf_[fj] = *(const bf16x8*)&lsB[(wc * 64 + fj * 16 + lr) * 64 + ks * 32 + lg * 8];
#pragma unroll
      for (int fi = 0; fi < 4; fi++)
#pragma unroll
        for (int fj = 0; fj < 4; fj++)
          acc[fi][fj] = __builtin_amdgcn_mfma_f32_16x16x32_bf16(af[fi], bf_[fj], acc[fi][fj], 0, 0, 0);
    }
    __syncthreads();
  }
}

// ---------------- QKV projection with layout-specializing epilogues ----------------
// z=0: Q energy-B-frag tiles [b][nt64][h*2+ks][lane][8], pre-scaled by log2(e)
// z=1: K energy-A-frag tiles [hp][kt64][h_lab16][ks2][lane][8]  (einsum's swapped K)
// z=2: V PV-B-frag tiles [b*16+h][kc32][dt4][lane][8]
__global__ __launch_bounds__(256, 2) void proj_qkv(
    const unsigned short* __restrict__ X, const unsigned short* __restrict__ W3,
    const float* __restrict__ bq, const float* __restrict__ bk, const float* __restrict__ bv,
    unsigned short* __restrict__ outq, unsigned short* __restrict__ outk, unsigned short* __restrict__ outv) {
  __shared__ unsigned short lsA[128 * 64];
  __shared__ unsigned short lsB[128 * 64];
  const int z = blockIdx.z;
  const int m0 = blockIdx.x * 128, n0 = blockIdx.y * 128;
  const unsigned short* Bw = W3 + z * 1048576;
  f32x4 acc[4][4];
  const f32x4 z4 = {0.f, 0.f, 0.f, 0.f};
#pragma unroll
  for (int i = 0; i < 4; i++)
#pragma unroll
    for (int j = 0; j < 4; j++) acc[i][j] = z4;
  gemm_tile(X, Bw, m0, n0, lsA, lsB, acc);

  const int tid = threadIdx.x;
  const int w = tid >> 6, l = tid & 63, lg = l >> 4, lr = l & 15, wr = w >> 1, wc = w & 1;
  const float* bias = (z == 0) ? bq : ((z == 1) ? bk : bv);
  const float SC = 1.4426950408889634f;  // log2(e), folded into Q
#pragma unroll
  for (int fi = 0; fi < 4; fi++) {
    const int mb = m0 + wr * 64 + fi * 16 + lg * 4;
#pragma unroll
    for (int fj = 0; fj < 4; fj++) {
      const int ncol = n0 + wc * 64 + fj * 16 + lr;
      const float bsv = bias[ncol];
      const int h = ncol >> 6, d = ncol & 63;
      if (z == 0) {
        const int ks = d >> 5, lgq = (d >> 3) & 3, eq = d & 7;
#pragma unroll
        for (int r = 0; r < 4; r++) {
          const int m = mb + r;
          const int bb = m >> 10, nr = m & 1023;
          const int nt = nr >> 4, lrq = nr & 15;
          const int idx = (((bb * 64 + nt) * 32 + h * 2 + ks) * 64 + lgq * 16 + lrq) * 8 + eq;
          outq[idx] = f2bf((acc[fi][fj][r] + bsv) * SC);
        }
      } else if (z == 1) {
        // energy A-frag: lane = ((d&31)>>3)*16 + (k&15), tile kt = k>>4, 32-chunk ks = d>>5
        const int ks = d >> 5, lhi = ((d >> 3) & 3) * 16, eq = d & 7;
#pragma unroll
        for (int r = 0; r < 4; r++) {
          const int m = mb + r;
          const int n = m & 1023, bx = m >> 10;  // n = k-position, bx = einsum h-label
          const int lane = lhi + (n & 15);
          const int idx = ((((h * 64 + (n >> 4)) * 16 + bx) * 2 + ks) * 64 + lane) * 8 + eq;
          outk[idx] = f2bf(acc[fi][fj][r] + bsv);
        }
      } else {
        const int dt = d >> 4, lrv = d & 15;
        const int bb = mb >> 10, n = mb & 1023;
        const int kc = n >> 5, lgv = (n >> 3) & 3, ev = n & 7;
        u16x4 pk;
#pragma unroll
        for (int r = 0; r < 4; r++) pk[r] = f2bf(acc[fi][fj][r] + bsv);
        const int idx0 = ((((bb * 16 + h) * 32 + kc) * 4 + dt) * 64 + lgv * 16 + lrv) * 8 + ev;
        *(u16x4*)&outv[idx0] = pk;
      }
    }
  }
}

// ---------------- output projection (fp32 out + bias) ----------------
__global__ __launch_bounds__(256, 2) void proj_out(
    const unsigned short* __restrict__ A, const unsigned short* __restrict__ Wp,
    const float* __restrict__ bias, float* __restrict__ out) {
  __shared__ unsigned short lsA[128 * 64];
  __shared__ unsigned short lsB[128 * 64];
  const int m0 = blockIdx.x * 128, n0 = blockIdx.y * 128;
  f32x4 acc[4][4];
  const f32x4 z4 = {0.f, 0.f, 0.f, 0.f};
#pragma unroll
  for (int i = 0; i < 4; i++)
#pragma unroll
    for (int j = 0; j < 4; j++) acc[i][j] = z4;
  gemm_tile(A, Wp, m0, n0, lsA, lsB, acc);
  const int tid = threadIdx.x;
  const int w = tid >> 6, l = tid & 63, lg = l >> 4, lr = l & 15, wr = w >> 1, wc = w & 1;
#pragma unroll
  for (int fi = 0; fi < 4; fi++) {
    const int mb = m0 + wr * 64 + fi * 16 + lg * 4;
#pragma unroll
    for (int fj = 0; fj < 4; fj++) {
      const int ncol = n0 + wc * 64 + fj * 16 + lr;
      const float bsv = bias[ncol];
#pragma unroll
      for (int r = 0; r < 4; r++) out[(mb + r) * 1024 + ncol] = acc[fi][fj][r] + bsv;
    }
  }
}

// ---------------- fused attention v5 ----------------
// attn4 structure (16 waves = 4ksub x 4hq, dedup K reads, lane-local h partials)
// with: 2 no-vmcnt-drain barriers/iter (separate 32KB sumbuf removes WAR barriers),
// K register double-buffer across iters, V issued before barrier B. 160KB LDS.
#define ATTN_BODY(IT, KC, KN)                                                  \
  {                                                                            \
    int qo = 0;                                                                \
    asm volatile("" : "+v"(qo));                                               \
    f32x4 e[4][2];                                                             \
    _Pragma("unroll") for (int hl = 0; hl < 4; hl++) {                         \
      const int h = hq * 4 + hl;                                               \
      _Pragma("unroll") for (int qh = 0; qh < 2; qh++) {                       \
        bf16x8 q0 = *(const bf16x8*)((const char*)qlds + qo + (qh * 32 + h * 2 + 0) * 1024 + l * 16); \
        bf16x8 q1 = *(const bf16x8*)((const char*)qlds + qo + (qh * 32 + h * 2 + 1) * 1024 + l * 16); \
        f32x4 t = __builtin_amdgcn_mfma_f32_16x16x32_bf16(KC[hl * 2 + 0], q0, z4, 0, 0, 0); \
        t = __builtin_amdgcn_mfma_f32_16x16x32_bf16(KC[hl * 2 + 1], q1, t, 0, 0, 0); \
        t[0] = fexp2(t[0]); t[1] = fexp2(t[1]); t[2] = fexp2(t[2]); t[3] = fexp2(t[3]); \
        e[hl][qh] = t;                                                         \
      }                                                                        \
    }                                                                          \
    {                                                                          \
      const unsigned short* knp = kroot + (size_t)((((IT) + 1) & 15) * 4) * 16384; \
      _Pragma("unroll") for (int i = 0; i < 8; i++) KN[i] = *(const bf16x8*)(knp + i * 512); \
    }                                                                          \
    f32x4 s0 = (e[0][0] + e[1][0]) + (e[2][0] + e[3][0]);                      \
    f32x4 s1 = (e[0][1] + e[1][1]) + (e[2][1] + e[3][1]);                      \
    *(f32x4*)&sumbuf[((ksub * 4 + hq) * 2 + 0) * 256 + l * 4] = s0;            \
    *(f32x4*)&sumbuf[((ksub * 4 + hq) * 2 + 1) * 256 + l * 4] = s1;            \
    wg_barrier();                                                              \
    _Pragma("unroll") for (int p = 1; p < 4; p++) {                            \
      const int hqp = hq ^ p;                                                  \
      s0 += *(const f32x4*)&sumbuf[((ksub * 4 + hqp) * 2 + 0) * 256 + l * 4];  \
      s1 += *(const f32x4*)&sumbuf[((ksub * 4 + hqp) * 2 + 1) * 256 + l * 4];  \
    }                                                                          \
    f32x4 inv0, inv1;                                                          \
    inv0[0] = frcp(s0[0]) * 0.03125f; inv0[1] = frcp(s0[1]) * 0.03125f;        \
    inv0[2] = frcp(s0[2]) * 0.03125f; inv0[3] = frcp(s0[3]) * 0.03125f;        \
    inv1[0] = frcp(s1[0]) * 0.03125f; inv1[1] = frcp(s1[1]) * 0.03125f;        \
    inv1[2] = frcp(s1[2]) * 0.03125f; inv1[3] = frcp(s1[3]) * 0.03125f;        \
    _Pragma("unroll") for (int hl = 0; hl < 4; hl++) {                         \
      const int h = hq * 4 + hl;                                               \
      _Pragma("unroll") for (int qh = 0; qh < 2; qh++) {                       \
        f32x4 vv = e[hl][qh] * (qh ? inv1 : inv0);                             \
        uint2 pk;                                                              \
        pk.x = cvtpk(vv[0], vv[1]);                                            \
        pk.y = cvtpk(vv[2], vv[3]);                                            \
        *(uint2*)((char*)abuf + h * 4096 + (qh * 16 + lr) * 128 + ((kpart ^ wswz) << 1)) = pk; \
      }                                                                        \
    }                                                                          \
    {                                                                          \
      const unsigned short* vbp = vroot + (size_t)((IT) * 2) * 2048;           \
      _Pragma("unroll") for (int kst = 0; kst < 2; kst++)                      \
        _Pragma("unroll") for (int dt = 0; dt < 4; dt++)                       \
          vr[kst * 4 + dt] = *(const bf16x8*)(vbp + kst * 2048 + dt * 512);    \
    }                                                                          \
    wg_barrier();                                                              \
    bf16x8 pa[2][2];                                                           \
    _Pragma("unroll") for (int qt = 0; qt < 2; qt++)                           \
      _Pragma("unroll") for (int kst = 0; kst < 2; kst++)                      \
        pa[qt][kst] = *(const bf16x8*)((const char*)abuf + w * 4096 + qt * 2048 + lr * 128 + (((kst * 4 + lg) ^ (lr & 7)) << 4)); \
    _Pragma("unroll") for (int qt = 0; qt < 2; qt++)                           \
      _Pragma("unroll") for (int kst = 0; kst < 2; kst++)                      \
        _Pragma("unroll") for (int dt = 0; dt < 4; dt++)                       \
          oacc[qt][dt] = __builtin_amdgcn_mfma_f32_16x16x32_bf16(pa[qt][kst], vr[kst * 4 + dt], oacc[qt][dt], 0, 0, 0); \
  }

__global__ __launch_bounds__(1024, 4) void attn5(
    const unsigned short* __restrict__ Q2,  // [b][nt64][h*2+ks][lane][8]
    const unsigned short* __restrict__ K2,  // [hp][kt64][h_lab16][ks2][lane][8]
    const unsigned short* __restrict__ V2,  // [b*16+h][kc32][dt4][lane][8]
    unsigned short* __restrict__ O) {       // [16][1024][1024] natural
  __shared__ unsigned short qlds[32768];  // 64 KB Q fragments (loaded once)
  __shared__ unsigned short abuf[32768];  // 64 KB att, XOR-swizzled
  __shared__ float sumbuf[8192];          // 32 KB partial h-sum exchange

  const int tid = threadIdx.x;
  const int w = tid >> 6, l = tid & 63;
  const int lr = l & 15, lg = l >> 4;
  const int bid = blockIdx.x;
  const int swz = (bid & 7) * 64 + (bid >> 3);  // XCD-chunked
  const int b = swz >> 5, qt32 = swz & 31;
  const int ksub = w & 3, hq = w >> 2;  // energy role; PV role: h = w

  // ---- stage Q once: 64 KB contiguous ----
  {
    const unsigned short* qsrc = Q2 + (size_t)(b * 64 + qt32 * 2) * 16384 + tid * 8;
    unsigned short* qdst = qlds + tid * 8;
#pragma unroll
    for (int r = 0; r < 4; r++) gload_lds16(qsrc + r * 8192, qdst + r * 8192);
  }

  const int kpart = ksub * 16 + lg * 4;   // k-elem base of my 4 acc slots
  const int wswz = (lr & 7) << 3;

  const f32x4 z4 = {0.f, 0.f, 0.f, 0.f};
  f32x4 oacc[2][4];
#pragma unroll
  for (int qt = 0; qt < 2; qt++)
#pragma unroll
    for (int dt = 0; dt < 4; dt++) oacc[qt][dt] = z4;

  const unsigned short* kroot = K2 + (size_t)(b * 64 + ksub) * 16384 + hq * 4096 + l * 8;
  const unsigned short* vroot = V2 + (size_t)((b * 16 + w) * 32) * 2048 + l * 8;

  // prologue: K[0] into regs (can issue before the Q barrier)
  bf16x8 kA[8], kB[8], vr[8];
#pragma unroll
  for (int i = 0; i < 8; i++) kA[i] = *(const bf16x8*)(kroot + i * 512);

  // Q staged via global_load_lds -> needs full vmcnt drain once
  asm volatile("s_waitcnt vmcnt(0) lgkmcnt(0)" ::: "memory");
  __builtin_amdgcn_s_barrier();
  __builtin_amdgcn_sched_barrier(0);

#pragma unroll 1
  for (int it2 = 0; it2 < 8; it2++) {
    ATTN_BODY(it2 * 2, kA, kB)
    ATTN_BODY(it2 * 2 + 1, kB, kA)
  }

  // ---- epilogue: O natural [b][n][e], my head h = w ----
#pragma unroll
  for (int qt = 0; qt < 2; qt++)
#pragma unroll
    for (int dt = 0; dt < 4; dt++)
#pragma unroll
      for (int r = 0; r < 4; r++) {
        const int n = qt32 * 32 + qt * 16 + lg * 4 + r;
        O[(size_t)(b * 1024 + n) * 1024 + w * 64 + dt * 16 + lr] = f2bf(oacc[qt][dt][r]);
      }
}

extern "C" void kernel_launch(void* const* d_in, const int* in_sizes, int n_in,
                              void* d_out, int out_size, void* d_ws, size_t ws_size,
                              hipStream_t stream) {
  const float* x  = (const float*)d_in[0];
  const float* Wq = (const float*)d_in[1];
  const float* bq = (const float*)d_in[2];
  const float* Wk = (const float*)d_in[3];
  const float* bk = (const float*)d_in[4];
  const float* Wv = (const float*)d_in[5];
  const float* bv = (const float*)d_in[6];
  const float* Wp = (const float*)d_in[7];
  const float* bp = (const float*)d_in[8];

  char* ws = (char*)d_ws;
  unsigned short* xbf  = (unsigned short*)(ws);              // 32 MiB; reused for O after attention
  unsigned short* qbf  = (unsigned short*)(ws + 33554432);   // Q2 fragment tiles
  unsigned short* kbf  = (unsigned short*)(ws + 67108864);   // K2 fragment tiles
  unsigned short* vtbf = (unsigned short*)(ws + 100663296);  // V2 fragment tiles
  unsigned short* wbf  = (unsigned short*)(ws + 134217728);  // Wq,Wk,Wv,Wp bf16 (4 x 2 MiB)

  cvt_kernel<<<2048, 256, 0, stream>>>(x, xbf, 4194304);
  cvt_kernel<<<512, 256, 0, stream>>>(Wq, wbf, 262144);
  cvt_kernel<<<512, 256, 0, stream>>>(Wk, wbf + 1048576, 262144);
  cvt_kernel<<<512, 256, 0, stream>>>(Wv, wbf + 2097152, 262144);
  cvt_kernel<<<512, 256, 0, stream>>>(Wp, wbf + 3145728, 262144);

  proj_qkv<<<dim3(128, 8, 3), 256, 0, stream>>>(xbf, wbf, bq, bk, bv, qbf, kbf, vtbf);
  attn5<<<512, 1024, 0, stream>>>(qbf, kbf, vtbf, xbf);
  proj_out<<<dim3(128, 8, 1), 256, 0, stream>>>(xbf, wbf + 3145728, bp, (float*)d_out);
}